// Round 1
// baseline (6561.230 us; speedup 1.0000x reference)
//
#include <hip/hip_runtime.h>
#include <hip/hip_bf16.h>

#define VV 50304
#define DD 1024
#define LL 2
#define HH 16
#define HKVH 8
#define HDD 64
#define EE 64
#define II 512
#define KTOP 2
#define BBA 2
#define SSQ 1024
#define TT 2048
#define CCAP 64

// ---------------- rope tables ----------------
__global__ void k_rope_tables(float* __restrict__ tabc, float* __restrict__ tabs) {
    int id = blockIdx.x * 256 + threadIdx.x;
    if (id >= SSQ * 32) return;
    int s = id >> 5, j = id & 31;
    double inv = pow(10000.0, -(double)j / 32.0);
    double ang = (double)s * inv;
    tabc[id] = (float)cos(ang);
    tabs[id] = (float)sin(ang);
}

// ---------------- embedding gather ----------------
__global__ __launch_bounds__(256) void k_embed(const int* __restrict__ ids,
                                               const float* __restrict__ embed,
                                               float* __restrict__ x) {
    int t = blockIdx.x;
    int id = ids[t];
    const float4* src = (const float4*)(embed + (size_t)id * DD);
    float4* dst = (float4*)(x + (size_t)t * DD);
    dst[threadIdx.x] = src[threadIdx.x];
}

// ---------------- RMS norm (row per block, D=1024) ----------------
__global__ __launch_bounds__(256) void k_rms(const float* __restrict__ x,
                                             const float* __restrict__ w,
                                             float* __restrict__ out, float eps) {
    __shared__ float sred[4];
    int row = blockIdx.x, tid = threadIdx.x;
    const float4* xr = (const float4*)(x + (size_t)row * DD);
    float4 v = xr[tid];
    float ss = v.x * v.x + v.y * v.y + v.z * v.z + v.w * v.w;
#pragma unroll
    for (int m = 32; m >= 1; m >>= 1) ss += __shfl_xor(ss, m, 64);
    if ((tid & 63) == 0) sred[tid >> 6] = ss;
    __syncthreads();
    float tot = sred[0] + sred[1] + sred[2] + sred[3];
    float sc = rsqrtf(tot * (1.0f / DD) + eps);
    const float4* wr = (const float4*)w;
    float4 wv = wr[tid];
    float4 o;
    o.x = v.x * sc * wv.x; o.y = v.y * sc * wv.y;
    o.z = v.z * sc * wv.z; o.w = v.w * sc * wv.w;
    ((float4*)(out + (size_t)row * DD))[tid] = o;
}

// ---------------- generic NN GEMM: C[M,N] = A[M,K] @ B[K,N] (+addsrc), batched over z ----------------
__global__ __launch_bounds__(256) void k_gemm_nn(
    const float* __restrict__ A, const float* __restrict__ B,
    float* __restrict__ Cm, const float* __restrict__ addsrc,
    int M, int N, int Kd, long long sA, long long sB, long long sC) {
    __shared__ __align__(16) float As[32][68];
    __shared__ __align__(16) float Bs[32][68];
    const float* Ab = A + (size_t)blockIdx.z * sA;
    const float* Bb = B + (size_t)blockIdx.z * sB;
    float* Cb = Cm + (size_t)blockIdx.z * sC;
    int m0 = blockIdx.y << 6, n0 = blockIdx.x << 6;
    int tid = threadIdx.x;
    int tx = tid & 15, ty = tid >> 4;
    int ar = tid >> 3, ac = (tid & 7) << 2;
    int br = tid >> 4, bc = (tid & 15) << 2;
    float acc[4][4] = {{0.f}};
    for (int k0 = 0; k0 < Kd; k0 += 32) {
        float4 a0 = *(const float4*)(Ab + (size_t)(m0 + ar) * Kd + k0 + ac);
        float4 a1 = *(const float4*)(Ab + (size_t)(m0 + ar + 32) * Kd + k0 + ac);
        float4 b0 = *(const float4*)(Bb + (size_t)(k0 + br) * N + n0 + bc);
        float4 b1 = *(const float4*)(Bb + (size_t)(k0 + br + 16) * N + n0 + bc);
        __syncthreads();
        As[ac + 0][ar] = a0.x; As[ac + 1][ar] = a0.y; As[ac + 2][ar] = a0.z; As[ac + 3][ar] = a0.w;
        As[ac + 0][ar + 32] = a1.x; As[ac + 1][ar + 32] = a1.y; As[ac + 2][ar + 32] = a1.z; As[ac + 3][ar + 32] = a1.w;
        *(float4*)&Bs[br][bc] = b0;
        *(float4*)&Bs[br + 16][bc] = b1;
        __syncthreads();
#pragma unroll
        for (int kk = 0; kk < 32; kk++) {
            float4 av = *(const float4*)&As[kk][ty << 2];
            float4 bv = *(const float4*)&Bs[kk][tx << 2];
            acc[0][0] += av.x * bv.x; acc[0][1] += av.x * bv.y; acc[0][2] += av.x * bv.z; acc[0][3] += av.x * bv.w;
            acc[1][0] += av.y * bv.x; acc[1][1] += av.y * bv.y; acc[1][2] += av.y * bv.z; acc[1][3] += av.y * bv.w;
            acc[2][0] += av.z * bv.x; acc[2][1] += av.z * bv.y; acc[2][2] += av.z * bv.z; acc[2][3] += av.z * bv.w;
            acc[3][0] += av.w * bv.x; acc[3][1] += av.w * bv.y; acc[3][2] += av.w * bv.z; acc[3][3] += av.w * bv.w;
        }
    }
#pragma unroll
    for (int i = 0; i < 4; i++) {
        int row = m0 + (ty << 2) + i;
        size_t cidx = (size_t)row * N + n0 + (tx << 2);
        float4 outv = make_float4(acc[i][0], acc[i][1], acc[i][2], acc[i][3]);
        if (addsrc) {
            float4 ad = *(const float4*)(addsrc + (size_t)blockIdx.z * sC + cidx);
            outv.x += ad.x; outv.y += ad.y; outv.z += ad.z; outv.w += ad.w;
        }
        *(float4*)(Cb + cidx) = outv;
    }
}

// ---------------- NT GEMM for logits: C[M,N] = A[M,K] @ B[N,K]^T, BM=128 BN=64 BK=32 ----------------
__global__ __launch_bounds__(256) void k_gemm_nt(
    const float* __restrict__ A, const float* __restrict__ B,
    float* __restrict__ Cm, int M, int N, int Kd) {
    __shared__ __align__(16) float As[32][132];
    __shared__ __align__(16) float Bs[32][68];
    int m0 = blockIdx.y << 7, n0 = blockIdx.x << 6;
    int tid = threadIdx.x;
    int tx = tid & 15, ty = tid >> 4;
    int ar = tid >> 3, ac = (tid & 7) << 2;
    float acc[8][4] = {{0.f}};
    for (int k0 = 0; k0 < Kd; k0 += 32) {
        float4 a0 = *(const float4*)(A + (size_t)(m0 + ar) * Kd + k0 + ac);
        float4 a1 = *(const float4*)(A + (size_t)(m0 + ar + 32) * Kd + k0 + ac);
        float4 a2 = *(const float4*)(A + (size_t)(m0 + ar + 64) * Kd + k0 + ac);
        float4 a3 = *(const float4*)(A + (size_t)(m0 + ar + 96) * Kd + k0 + ac);
        float4 b0 = *(const float4*)(B + (size_t)(n0 + ar) * Kd + k0 + ac);
        float4 b1 = *(const float4*)(B + (size_t)(n0 + ar + 32) * Kd + k0 + ac);
        __syncthreads();
        As[ac + 0][ar] = a0.x; As[ac + 1][ar] = a0.y; As[ac + 2][ar] = a0.z; As[ac + 3][ar] = a0.w;
        As[ac + 0][ar + 32] = a1.x; As[ac + 1][ar + 32] = a1.y; As[ac + 2][ar + 32] = a1.z; As[ac + 3][ar + 32] = a1.w;
        As[ac + 0][ar + 64] = a2.x; As[ac + 1][ar + 64] = a2.y; As[ac + 2][ar + 64] = a2.z; As[ac + 3][ar + 64] = a2.w;
        As[ac + 0][ar + 96] = a3.x; As[ac + 1][ar + 96] = a3.y; As[ac + 2][ar + 96] = a3.z; As[ac + 3][ar + 96] = a3.w;
        Bs[ac + 0][ar] = b0.x; Bs[ac + 1][ar] = b0.y; Bs[ac + 2][ar] = b0.z; Bs[ac + 3][ar] = b0.w;
        Bs[ac + 0][ar + 32] = b1.x; Bs[ac + 1][ar + 32] = b1.y; Bs[ac + 2][ar + 32] = b1.z; Bs[ac + 3][ar + 32] = b1.w;
        __syncthreads();
#pragma unroll
        for (int kk = 0; kk < 32; kk++) {
            float4 av0 = *(const float4*)&As[kk][ty << 3];
            float4 av1 = *(const float4*)&As[kk][(ty << 3) + 4];
            float4 bv = *(const float4*)&Bs[kk][tx << 2];
            acc[0][0] += av0.x * bv.x; acc[0][1] += av0.x * bv.y; acc[0][2] += av0.x * bv.z; acc[0][3] += av0.x * bv.w;
            acc[1][0] += av0.y * bv.x; acc[1][1] += av0.y * bv.y; acc[1][2] += av0.y * bv.z; acc[1][3] += av0.y * bv.w;
            acc[2][0] += av0.z * bv.x; acc[2][1] += av0.z * bv.y; acc[2][2] += av0.z * bv.z; acc[2][3] += av0.z * bv.w;
            acc[3][0] += av0.w * bv.x; acc[3][1] += av0.w * bv.y; acc[3][2] += av0.w * bv.z; acc[3][3] += av0.w * bv.w;
            acc[4][0] += av1.x * bv.x; acc[4][1] += av1.x * bv.y; acc[4][2] += av1.x * bv.z; acc[4][3] += av1.x * bv.w;
            acc[5][0] += av1.y * bv.x; acc[5][1] += av1.y * bv.y; acc[5][2] += av1.y * bv.z; acc[5][3] += av1.y * bv.w;
            acc[6][0] += av1.z * bv.x; acc[6][1] += av1.z * bv.y; acc[6][2] += av1.z * bv.z; acc[6][3] += av1.z * bv.w;
            acc[7][0] += av1.w * bv.x; acc[7][1] += av1.w * bv.y; acc[7][2] += av1.w * bv.z; acc[7][3] += av1.w * bv.w;
        }
    }
#pragma unroll
    for (int i = 0; i < 8; i++) {
        int row = m0 + (ty << 3) + i;
        float4 outv = make_float4(acc[i][0], acc[i][1], acc[i][2], acc[i][3]);
        *(float4*)(Cm + (size_t)row * N + n0 + (tx << 2)) = outv;
    }
}

// ---------------- per-head RMS norm + RoPE (in place), one 64-lane group per row ----------------
__global__ __launch_bounds__(256) void k_qknorm_rope(float* __restrict__ x, const float* __restrict__ w,
                                                     const float* __restrict__ tabc, const float* __restrict__ tabs,
                                                     int heads) {
    int row = blockIdx.x * 4 + (threadIdx.x >> 6);
    int lane = threadIdx.x & 63;
    int t = row / heads;
    int s = t & (SSQ - 1);
    size_t base = (size_t)row * 64;
    float val = x[base + lane];
    float ss = val * val;
#pragma unroll
    for (int m = 32; m >= 1; m >>= 1) ss += __shfl_xor(ss, m, 64);
    float sc = rsqrtf(ss * (1.0f / 64.0f) + 1e-5f);
    float xn = val * sc * w[lane];
    float other = __shfl_xor(xn, 32, 64);
    int j = lane & 31;
    float c = tabc[s * 32 + j], sn = tabs[s * 32 + j];
    float res = (lane < 32) ? (xn * c - other * sn) : (other * sn + xn * c);
    x[base + lane] = res;
}

// ---------------- fused causal attention, one block per (b,h,s) query row ----------------
__global__ __launch_bounds__(256) void k_attn(const float* __restrict__ q, const float* __restrict__ k,
                                              const float* __restrict__ v, float* __restrict__ o) {
    __shared__ __align__(16) float scb[SSQ];
    __shared__ __align__(16) float qs[64];
    __shared__ float sred[4];
    __shared__ float pvs[4][64];
    int idx = blockIdx.x;
    int s = idx & (SSQ - 1);
    int hh = (idx >> 10) & (HH - 1);
    int b = idx >> 14;
    int tid = threadIdx.x;
    int tbase = b * SSQ;
    int hk = hh >> 1;
    if (tid < 64) qs[tid] = q[((size_t)(tbase + s) * HH + hh) * 64 + tid];
    __syncthreads();
    for (int t = tid; t <= s; t += 256) {
        const float4* kr = (const float4*)(k + ((size_t)(tbase + t) * HKVH + hk) * 64);
        const float4* q4 = (const float4*)qs;
        float acc = 0.f;
#pragma unroll
        for (int jj = 0; jj < 16; jj++) {
            float4 kv = kr[jj]; float4 qv = q4[jj];
            acc += qv.x * kv.x + qv.y * kv.y + qv.z * kv.z + qv.w * kv.w;
        }
        scb[t] = acc * 0.125f;
    }
    __syncthreads();
    float m = -3.0e38f;
    for (int t = tid; t <= s; t += 256) m = fmaxf(m, scb[t]);
#pragma unroll
    for (int msk = 32; msk >= 1; msk >>= 1) m = fmaxf(m, __shfl_xor(m, msk, 64));
    if ((tid & 63) == 0) sred[tid >> 6] = m;
    __syncthreads();
    m = fmaxf(fmaxf(sred[0], sred[1]), fmaxf(sred[2], sred[3]));
    __syncthreads();
    float sum = 0.f;
    for (int t = tid; t <= s; t += 256) {
        float p = expf(scb[t] - m);
        scb[t] = p;
        sum += p;
    }
#pragma unroll
    for (int msk = 32; msk >= 1; msk >>= 1) sum += __shfl_xor(sum, msk, 64);
    if ((tid & 63) == 0) sred[tid >> 6] = sum;
    __syncthreads();
    sum = sred[0] + sred[1] + sred[2] + sred[3];
    float inv = 1.0f / sum;
    int d = tid & 63, g = tid >> 6;
    float accv = 0.f;
    for (int t = g; t <= s; t += 4)
        accv += scb[t] * v[((size_t)(tbase + t) * HKVH + hk) * 64 + d];
    pvs[g][d] = accv;
    __syncthreads();
    if (tid < 64) {
        float r = (pvs[0][tid] + pvs[1][tid] + pvs[2][tid] + pvs[3][tid]) * inv;
        o[((size_t)(tbase + s) * HH + hh) * 64 + tid] = r;
    }
}

// ---------------- o *= sigmoid(glin) ----------------
__global__ __launch_bounds__(256) void k_gate_mul(const float* __restrict__ glin, float* __restrict__ o) {
    size_t i = (size_t)blockIdx.x * 256 + threadIdx.x;
    float4 g4 = ((const float4*)glin)[i];
    float4 o4 = ((float4*)o)[i];
    o4.x *= 1.f / (1.f + expf(-g4.x));
    o4.y *= 1.f / (1.f + expf(-g4.y));
    o4.z *= 1.f / (1.f + expf(-g4.z));
    o4.w *= 1.f / (1.f + expf(-g4.w));
    ((float4*)o)[i] = o4;
}

// ---------------- router softmax + top-2, one 64-lane group per token ----------------
__global__ __launch_bounds__(256) void k_router(const float* __restrict__ rlog, int* __restrict__ ti,
                                                float* __restrict__ tw, int* __restrict__ slot_of) {
    int tok = blockIdx.x * 4 + (threadIdx.x >> 6);
    int lane = threadIdx.x & 63;
    float l = rlog[(size_t)tok * 64 + lane];
    float m = l;
#pragma unroll
    for (int msk = 32; msk >= 1; msk >>= 1) m = fmaxf(m, __shfl_xor(m, msk, 64));
    float p = expf(l - m);
    float ssum = p;
#pragma unroll
    for (int msk = 32; msk >= 1; msk >>= 1) ssum += __shfl_xor(ssum, msk, 64);
    float prob = p / ssum;
    float v1 = prob; int i1 = lane;
#pragma unroll
    for (int msk = 32; msk >= 1; msk >>= 1) {
        float ov = __shfl_xor(v1, msk, 64); int oi = __shfl_xor(i1, msk, 64);
        if (ov > v1 || (ov == v1 && oi < i1)) { v1 = ov; i1 = oi; }
    }
    float v2 = (lane == i1) ? -1.0f : prob; int i2 = lane;
#pragma unroll
    for (int msk = 32; msk >= 1; msk >>= 1) {
        float ov = __shfl_xor(v2, msk, 64); int oi = __shfl_xor(i2, msk, 64);
        if (ov > v2 || (ov == v2 && oi < i2)) { v2 = ov; i2 = oi; }
    }
    if (lane == 0) {
        float wsum = v1 + v2;
        ti[tok * 2] = i1; ti[tok * 2 + 1] = i2;
        tw[tok * 2] = v1 / wsum; tw[tok * 2 + 1] = v2 / wsum;
        slot_of[tok * 2] = -1; slot_of[tok * 2 + 1] = -1;
    }
}

// ---------------- deterministic capacity scan, one block per expert ----------------
__global__ __launch_bounds__(256) void k_moe_scan(const int* __restrict__ ti, int* __restrict__ slot_token,
                                                  int* __restrict__ slot_of, int* __restrict__ cnt) {
    __shared__ int sdat[256];
    int e = blockIdx.x, tid = threadIdx.x;
    int running = 0;
    for (int base = 0; base < KTOP * TT; base += 256) {
        int p = base + tid;
        int kk = p >> 11, t = p & (TT - 1);
        int flag = (ti[t * 2 + kk] == e) ? 1 : 0;
        sdat[tid] = flag;
        __syncthreads();
#pragma unroll
        for (int off = 1; off < 256; off <<= 1) {
            int val = (tid >= off) ? sdat[tid - off] : 0;
            __syncthreads();
            sdat[tid] += val;
            __syncthreads();
        }
        int pos = running + sdat[tid] - flag;
        if (flag && pos < CCAP) {
            slot_token[e * CCAP + pos] = t;
            slot_of[t * 2 + kk] = e * CCAP + pos;
        }
        running += sdat[255];
        __syncthreads();
    }
    if (tid == 0) cnt[e] = running < CCAP ? running : CCAP;
}

// ---------------- gather token rows into expert slots (zero-fill unused) ----------------
__global__ __launch_bounds__(256) void k_gather(const float* __restrict__ h, const int* __restrict__ slot_token,
                                                const int* __restrict__ cnt, float* __restrict__ xe) {
    int slot = blockIdx.x;
    int e = slot >> 6, c = slot & 63;
    float4* dst = (float4*)(xe + (size_t)slot * DD);
    if (c < cnt[e]) {
        const float4* src = (const float4*)(h + (size_t)slot_token[slot] * DD);
        dst[threadIdx.x] = src[threadIdx.x];
    } else {
        dst[threadIdx.x] = make_float4(0.f, 0.f, 0.f, 0.f);
    }
}

// ---------------- a = silu(g) * u (in place into g) ----------------
__global__ __launch_bounds__(256) void k_silu_mul(float* __restrict__ g, const float* __restrict__ u) {
    size_t i = (size_t)blockIdx.x * 256 + threadIdx.x;
    float4 gv = ((float4*)g)[i];
    float4 uv = ((const float4*)u)[i];
    gv.x = gv.x / (1.f + expf(-gv.x)) * uv.x;
    gv.y = gv.y / (1.f + expf(-gv.y)) * uv.y;
    gv.z = gv.z / (1.f + expf(-gv.z)) * uv.z;
    gv.w = gv.w / (1.f + expf(-gv.w)) * uv.w;
    ((float4*)g)[i] = gv;
}

// ---------------- combine expert outputs back to tokens: x += sum_k w_k * eo[slot_k] ----------------
__global__ __launch_bounds__(256) void k_combine(float* __restrict__ x, const float* __restrict__ eo,
                                                 const int* __restrict__ slot_of, const float* __restrict__ tw) {
    int t = blockIdx.x;
    int s0 = slot_of[t * 2], s1 = slot_of[t * 2 + 1];
    float w0 = tw[t * 2], w1 = tw[t * 2 + 1];
    float4 acc = ((float4*)(x + (size_t)t * DD))[threadIdx.x];
    if (s0 >= 0) {
        float4 e0 = ((const float4*)(eo + (size_t)s0 * DD))[threadIdx.x];
        acc.x += w0 * e0.x; acc.y += w0 * e0.y; acc.z += w0 * e0.z; acc.w += w0 * e0.w;
    }
    if (s1 >= 0) {
        float4 e1 = ((const float4*)(eo + (size_t)s1 * DD))[threadIdx.x];
        acc.x += w1 * e1.x; acc.y += w1 * e1.y; acc.z += w1 * e1.z; acc.w += w1 * e1.w;
    }
    ((float4*)(x + (size_t)t * DD))[threadIdx.x] = acc;
}

extern "C" void kernel_launch(void* const* d_in, const int* in_sizes, int n_in,
                              void* d_out, int out_size, void* d_ws, size_t ws_size,
                              hipStream_t stream) {
    (void)in_sizes; (void)n_in; (void)out_size; (void)ws_size;
    const int* ids = (const int*)d_in[0];
    const float* embed = (const float*)d_in[1];
    const float* attn_norm_w = (const float*)d_in[2];
    const float* ffn_norm_w = (const float*)d_in[3];
    const float* Wq = (const float*)d_in[4];
    const float* Wk = (const float*)d_in[5];
    const float* Wv = (const float*)d_in[6];
    const float* Wo = (const float*)d_in[7];
    const float* Wg = (const float*)d_in[8];
    const float* q_norm_w = (const float*)d_in[9];
    const float* k_norm_w = (const float*)d_in[10];
    const float* router_w = (const float*)d_in[11];
    const float* We_gate = (const float*)d_in[12];
    const float* We_up = (const float*)d_in[13];
    const float* We_down = (const float*)d_in[14];
    const float* ln_f_w = (const float*)d_in[15];
    float* out = (float*)d_out;

    float* ws = (float*)d_ws;
    size_t off = 0;
    auto alloc = [&](size_t n) { float* p = ws + off; off += (n + 255) & ~(size_t)255; return p; };
    float* tabc = alloc(SSQ * 32);
    float* tabs = alloc(SSQ * 32);
    float* x = alloc((size_t)TT * DD);
    float* h = alloc((size_t)TT * DD);
    float* q = alloc((size_t)TT * 1024);
    float* kb = alloc((size_t)TT * 512);
    float* vb = alloc((size_t)TT * 512);
    float* glin = alloc((size_t)TT * 1024);
    float* ob = alloc((size_t)TT * 1024);
    float* rlog = alloc((size_t)TT * EE);
    float* tw = alloc(TT * 2);
    float* xe = alloc((size_t)EE * CCAP * DD);
    float* gb = alloc((size_t)EE * CCAP * II);
    float* ub = alloc((size_t)EE * CCAP * II);
    float* eo = alloc((size_t)EE * CCAP * DD);
    int* ti = (int*)alloc(TT * 2);
    int* slot_of = (int*)alloc(TT * 2);
    int* slot_token = (int*)alloc(EE * CCAP);
    int* cnt = (int*)alloc(EE);

    k_rope_tables<<<128, 256, 0, stream>>>(tabc, tabs);
    k_embed<<<TT, 256, 0, stream>>>(ids, embed, x);

    for (int l = 0; l < LL; l++) {
        const float* Wq_l = Wq + (size_t)l * DD * 1024;
        const float* Wk_l = Wk + (size_t)l * DD * 512;
        const float* Wv_l = Wv + (size_t)l * DD * 512;
        const float* Wo_l = Wo + (size_t)l * 1024 * DD;
        const float* Wg_l = Wg + (size_t)l * DD * 1024;
        const float* Weg_l = We_gate + (size_t)l * EE * DD * II;
        const float* Weu_l = We_up + (size_t)l * EE * DD * II;
        const float* Wed_l = We_down + (size_t)l * EE * II * DD;

        k_rms<<<TT, 256, 0, stream>>>(x, attn_norm_w + (size_t)l * DD, h, 1e-6f);
        k_gemm_nn<<<dim3(16, 32, 1), 256, 0, stream>>>(h, Wq_l, q, nullptr, TT, 1024, 1024, 0, 0, 0);
        k_gemm_nn<<<dim3(8, 32, 1), 256, 0, stream>>>(h, Wk_l, kb, nullptr, TT, 512, 1024, 0, 0, 0);
        k_gemm_nn<<<dim3(8, 32, 1), 256, 0, stream>>>(h, Wv_l, vb, nullptr, TT, 512, 1024, 0, 0, 0);
        k_gemm_nn<<<dim3(16, 32, 1), 256, 0, stream>>>(h, Wg_l, glin, nullptr, TT, 1024, 1024, 0, 0, 0);
        k_qknorm_rope<<<TT * HH / 4, 256, 0, stream>>>(q, q_norm_w + (size_t)l * 64, tabc, tabs, HH);
        k_qknorm_rope<<<TT * HKVH / 4, 256, 0, stream>>>(kb, k_norm_w + (size_t)l * 64, tabc, tabs, HKVH);
        k_attn<<<BBA * HH * SSQ, 256, 0, stream>>>(q, kb, vb, ob);
        k_gate_mul<<<2048, 256, 0, stream>>>(glin, ob);
        k_gemm_nn<<<dim3(16, 32, 1), 256, 0, stream>>>(ob, Wo_l, x, x, TT, 1024, 1024, 0, 0, 0);
        k_rms<<<TT, 256, 0, stream>>>(x, ffn_norm_w + (size_t)l * DD, h, 1e-6f);
        k_gemm_nn<<<dim3(1, 32, 1), 256, 0, stream>>>(h, router_w + (size_t)l * DD * EE, rlog, nullptr, TT, EE, 1024, 0, 0, 0);
        k_router<<<TT / 4, 256, 0, stream>>>(rlog, ti, tw, slot_of);
        k_moe_scan<<<EE, 256, 0, stream>>>(ti, slot_token, slot_of, cnt);
        k_gather<<<EE * CCAP, 256, 0, stream>>>(h, slot_token, cnt, xe);
        k_gemm_nn<<<dim3(8, 1, 64), 256, 0, stream>>>(xe, Weg_l, gb, nullptr, CCAP, II, DD,
                                                      (long long)CCAP * DD, (long long)DD * II, (long long)CCAP * II);
        k_gemm_nn<<<dim3(8, 1, 64), 256, 0, stream>>>(xe, Weu_l, ub, nullptr, CCAP, II, DD,
                                                      (long long)CCAP * DD, (long long)DD * II, (long long)CCAP * II);
        k_silu_mul<<<2048, 256, 0, stream>>>(gb, ub);
        k_gemm_nn<<<dim3(16, 1, 64), 256, 0, stream>>>(gb, Wed_l, eo, nullptr, CCAP, DD, II,
                                                       (long long)CCAP * II, (long long)II * DD, (long long)CCAP * DD);
        k_combine<<<TT, 256, 0, stream>>>(x, eo, slot_of, tw);
    }

    k_rms<<<TT, 256, 0, stream>>>(x, ln_f_w, h, 1e-6f);
    k_gemm_nt<<<dim3(VV / 64, TT / 128, 1), 256, 0, stream>>>(h, embed, out, TT, VV, 1024);
}